// Round 1
// baseline (1557.203 us; speedup 1.0000x reference)
//
#include <hip/hip_runtime.h>
#include <hip/hip_bf16.h>
#include <cstddef>

// Problem constants
// B=4, H=W=64, DIM=768, HEADS=12, HD=64, STRIDE=2, N=4097, pooled tokens=1025
#define NTOK 4097
#define NPOOL 1025
#define DIMC 768

// ---------------------------------------------------------------------------
// Generic f32 tiled GEMM: C[M,N] = A[M,K] @ B[K,N] (+bias). 64x64 tile, 4x4/thr.
// Requires K%16==0, N%64==0.
// ---------------------------------------------------------------------------
__global__ __launch_bounds__(256) void gemm_f32(const float* __restrict__ A,
                                                const float* __restrict__ B,
                                                const float* __restrict__ bias,
                                                float* __restrict__ C,
                                                int M, int N, int K) {
    __shared__ float As[16][68];
    __shared__ float Bs[16][68];
    const int tid = threadIdx.x;
    const int bm = blockIdx.y * 64, bn = blockIdx.x * 64;
    const int tx = tid & 15, ty = tid >> 4;
    float acc[4][4] = {};
    for (int k0 = 0; k0 < K; k0 += 16) {
#pragma unroll
        for (int i = 0; i < 4; ++i) {
            int e = tid + i * 256;          // 0..1023
            int m = e >> 4, kk = e & 15;
            int gm = bm + m;
            As[kk][m] = (gm < M) ? A[(size_t)gm * K + k0 + kk] : 0.f;
        }
#pragma unroll
        for (int i = 0; i < 4; ++i) {
            int e = tid + i * 256;
            int kk = e >> 6, n = e & 63;
            Bs[kk][n] = B[(size_t)(k0 + kk) * N + bn + n];
        }
        __syncthreads();
#pragma unroll
        for (int kk = 0; kk < 16; ++kk) {
            float4 av = *(const float4*)&As[kk][ty * 4];
            float4 bv = *(const float4*)&Bs[kk][tx * 4];
            float a[4] = {av.x, av.y, av.z, av.w};
            float b[4] = {bv.x, bv.y, bv.z, bv.w};
#pragma unroll
            for (int i2 = 0; i2 < 4; ++i2)
#pragma unroll
                for (int j = 0; j < 4; ++j) acc[i2][j] += a[i2] * b[j];
        }
        __syncthreads();
    }
#pragma unroll
    for (int i = 0; i < 4; ++i) {
        int gm = bm + ty * 4 + i;
        if (gm >= M) continue;
        float4 v = make_float4(acc[i][0], acc[i][1], acc[i][2], acc[i][3]);
        if (bias) {
            v.x += bias[bn + tx * 4 + 0];
            v.y += bias[bn + tx * 4 + 1];
            v.z += bias[bn + tx * 4 + 2];
            v.w += bias[bn + tx * 4 + 3];
        }
        *(float4*)&C[(size_t)gm * N + bn + tx * 4] = v;
    }
}

// ---------------------------------------------------------------------------
// Pool: depthwise 3x3 stride-2 SAME conv on the head-shuffled grid view,
// then per-(head,token) LayerNorm over 64 channels (wave-local reduce).
// pos == 1024 handles the cls token (straight from qkv, LN only).
// Writes pooled (b,12,1025,64); for K also writes transposed (b,12,64,1025).
// ---------------------------------------------------------------------------
__global__ __launch_bounds__(256) void pool_ln_kernel(
    const float* __restrict__ qkv,
    const float* __restrict__ dwq, const float* __restrict__ dwk, const float* __restrict__ dwv,
    const float* __restrict__ gq, const float* __restrict__ bq,
    const float* __restrict__ gk, const float* __restrict__ bk,
    const float* __restrict__ gv, const float* __restrict__ bv,
    float* __restrict__ qp, float* __restrict__ kp, float* __restrict__ vp,
    float* __restrict__ kt) {
    const int pos = blockIdx.x;          // 0..1023 spatial, 1024 = cls
    const int which = blockIdx.y;        // 0=q,1=k,2=v
    const int bi = blockIdx.z;
    const float* w   = which == 0 ? dwq : which == 1 ? dwk : dwv;
    const float* gam = which == 0 ? gq  : which == 1 ? gk  : gv;
    const float* bet = which == 0 ? bq  : which == 1 ? bk  : bv;
    float* outp      = which == 0 ? qp  : which == 1 ? kp  : vp;
    const int wave = threadIdx.x >> 6, lane = threadIdx.x & 63;
    const size_t base = (size_t)bi * NTOK * 2304 + (size_t)which * DIMC;

    for (int db = wave; db < 12; db += 4) {
        float val;
        int h, tok;
        if (pos == 1024) {
            h = db; tok = 0;
            val = qkv[base + (size_t)db * 64 + lane];   // token 0 (cls)
        } else {
            const int oh = pos >> 5, ow = pos & 31;
            const int d = db * 64 + lane;
            float acc = 0.f;
#pragma unroll
            for (int kh = 0; kh < 3; ++kh) {
                const int ih = oh * 2 + kh;             // pad_lo = 0
#pragma unroll
                for (int kw = 0; kw < 3; ++kw) {
                    const int iw = ow * 2 + kw;
                    if (ih < 64 && iw < 64) {
                        const int m = (ih * 64 + iw) * DIMC + d;   // grid-flat offset
                        const int hin = m >> 18;                    // /262144
                        const int l   = (m >> 6) & 4095;
                        const int ci  = m & 63;
                        acc += qkv[base + (size_t)(1 + l) * 2304 + hin * 64 + ci]
                             * w[(kh * 3 + kw) * DIMC + d];
                    }
                }
            }
            val = acc;
            const int idx = pos * 12 + db;              // pooled 64-block index
            h = idx >> 10;
            tok = 1 + (idx & 1023);
        }
        // LayerNorm over 64 lanes (ci == lane)
        float s = val;
#pragma unroll
        for (int o = 32; o > 0; o >>= 1) s += __shfl_xor(s, o);
        const float mu = s * (1.f / 64.f);
        const float dv = val - mu;
        float s2 = dv * dv;
#pragma unroll
        for (int o = 32; o > 0; o >>= 1) s2 += __shfl_xor(s2, o);
        const float inv = rsqrtf(s2 * (1.f / 64.f) + 1e-3f);
        const float res = dv * inv * gam[lane] + bet[lane];
        outp[((size_t)(bi * 12 + h) * NPOOL + tok) * 64 + lane] = res;
        if (which == 1)
            kt[((size_t)(bi * 12 + h) * 64 + lane) * NPOOL + tok] = res;
    }
}

// ---------------------------------------------------------------------------
// rel tables: relH[b,y,qh,qw,kh] = sum_c qpool[b,y,tok,c]*rel_pos_h[qh-kh+31][c]
// One wave per q row; lanes 0..31 -> kh, 32..63 -> kw.
// ---------------------------------------------------------------------------
__global__ __launch_bounds__(256) void rel_kernel(const float* __restrict__ qp,
                                                  const float* __restrict__ rph,
                                                  const float* __restrict__ rpw,
                                                  float* __restrict__ relH,
                                                  float* __restrict__ relW) {
    __shared__ float qs[4][64];
    const int wave = threadIdx.x >> 6, lane = threadIdx.x & 63;
    const int r = blockIdx.x * 4 + wave;         // 0..49151 = (b*12+y)*1024+pos
    const int bh = r >> 10, pos = r & 1023;
    const int qh = pos >> 5, qw = pos & 31;
    qs[wave][lane] = qp[((size_t)bh * NPOOL + 1 + pos) * 64 + lane];
    __syncthreads();
    const int kj = lane & 31;
    const float* tab = (lane < 32) ? (rph + (qh - kj + 31) * 64)
                                   : (rpw + (qw - kj + 31) * 64);
    float acc = 0.f;
#pragma unroll
    for (int c = 0; c < 64; ++c) acc += qs[wave][c] * tab[c];
    if (lane < 32) relH[(size_t)r * 32 + kj] = acc;
    else           relW[(size_t)r * 32 + kj] = acc;
}

// ---------------------------------------------------------------------------
// Attention: per block = (b*12+h, 8 q-rows). Two-pass softmax with the 8x1025
// logit tile in LDS. rel_h/rel_w gathered per (q,k). PV + residual + write to
// out_pre in (b, tok, head*64+c) layout.
// ---------------------------------------------------------------------------
__global__ __launch_bounds__(256) void attn_kernel(
    const float* __restrict__ qp, const float* __restrict__ kt, const float* __restrict__ vp,
    const float* __restrict__ relH, const float* __restrict__ relW,
    float* __restrict__ outp) {
    __shared__ float logits[8][1028];
    __shared__ float qst[64][8];     // q transposed: [c][qi]
    __shared__ float srow[8];
    const int bh = blockIdx.y;       // 0..47
    const int bi = bh / 12, hh = bh % 12;
    const int q0 = blockIdx.x * 8;
    const int tid = threadIdx.x;

    for (int i = tid; i < 512; i += 256) {
        const int qi = i >> 6, c = i & 63;
        const int qr = q0 + qi;
        qst[c][qi] = (qr < NPOOL) ? qp[((size_t)bh * NPOOL + qr) * 64 + c] : 0.f;
    }
    __syncthreads();

    const float* KT = kt + (size_t)bh * 64 * NPOOL;
    for (int kc = 0; kc < NPOOL; kc += 256) {
        const int k = kc + tid;
        if (k < NPOOL) {
            float acc[8] = {0, 0, 0, 0, 0, 0, 0, 0};
            for (int c = 0; c < 64; ++c) {
                const float kv = KT[c * NPOOL + k];
                const float4 a0 = *(const float4*)&qst[c][0];
                const float4 a1 = *(const float4*)&qst[c][4];
                acc[0] += a0.x * kv; acc[1] += a0.y * kv;
                acc[2] += a0.z * kv; acc[3] += a0.w * kv;
                acc[4] += a1.x * kv; acc[5] += a1.y * kv;
                acc[6] += a1.z * kv; acc[7] += a1.w * kv;
            }
            const int kk = k - 1;
            const int kh = kk >> 5, kwj = kk & 31;
#pragma unroll
            for (int qi = 0; qi < 8; ++qi) {
                const int qr = q0 + qi;
                float v = acc[qi] * 0.125f;          // scale = HD^-0.5
                if (k >= 1 && qr >= 1 && qr < NPOOL) {
                    const size_t rb = ((size_t)bh * 1024 + (qr - 1)) * 32;
                    v += relH[rb + kh] + relW[rb + kwj];
                }
                logits[qi][k] = v;
            }
        }
    }
    __syncthreads();

    const int wave = tid >> 6, lane = tid & 63;
    for (int qi = wave; qi < 8; qi += 4) {
        if (q0 + qi >= NPOOL) break;                 // wave-uniform
        float m = -3.0e38f;
        for (int k = lane; k < NPOOL; k += 64) m = fmaxf(m, logits[qi][k]);
#pragma unroll
        for (int o = 32; o > 0; o >>= 1) m = fmaxf(m, __shfl_xor(m, o));
        float s = 0.f;
        for (int k = lane; k < NPOOL; k += 64) {
            const float p = __expf(logits[qi][k] - m);
            logits[qi][k] = p;
            s += p;
        }
#pragma unroll
        for (int o = 32; o > 0; o >>= 1) s += __shfl_xor(s, o);
        if (lane == 0) srow[qi] = s;
    }
    __syncthreads();

    const int c = tid & 63, g = tid >> 6;
    const float* V = vp + (size_t)bh * NPOOL * 64;
    float acc0 = 0.f, acc1 = 0.f;
    for (int k = 0; k < NPOOL; ++k) {
        const float vv = V[(size_t)k * 64 + c];
        acc0 += logits[g][k] * vv;
        acc1 += logits[g + 4][k] * vv;
    }
    {
        const int qr = q0 + g;
        if (qr < NPOOL) {
            const float o = acc0 / srow[g] + qst[c][g];
            outp[((size_t)bi * NPOOL + qr) * DIMC + hh * 64 + c] = o;
        }
        const int qr2 = q0 + g + 4;
        if (qr2 < NPOOL) {
            const float o = acc1 / srow[g + 4] + qst[c][g + 4];
            outp[((size_t)bi * NPOOL + qr2) * DIMC + hh * 64 + c] = o;
        }
    }
}

// ---------------------------------------------------------------------------
extern "C" void kernel_launch(void* const* d_in, const int* in_sizes, int n_in,
                              void* d_out, int out_size, void* d_ws, size_t ws_size,
                              hipStream_t stream) {
    const float* x     = (const float*)d_in[0];
    const float* wqkv  = (const float*)d_in[1];
    const float* dwq   = (const float*)d_in[2];
    const float* dwk   = (const float*)d_in[3];
    const float* dwv   = (const float*)d_in[4];
    const float* gq    = (const float*)d_in[5];
    const float* bq    = (const float*)d_in[6];
    const float* gk    = (const float*)d_in[7];
    const float* bk    = (const float*)d_in[8];
    const float* gv    = (const float*)d_in[9];
    const float* bv    = (const float*)d_in[10];
    const float* rph   = (const float*)d_in[11];
    const float* rpw   = (const float*)d_in[12];
    const float* wproj = (const float*)d_in[13];
    const float* bproj = (const float*)d_in[14];
    float* out = (float*)d_out;
    float* ws  = (float*)d_ws;

    // Workspace layout (floats). qkv_full region recycled for rel/out_pre
    // once pooling has consumed it.
    float* qkv_full = ws;                                   // 4*4097*2304 = 37,757,952
    float* qp = qkv_full + (size_t)37757952;                // 4*12*1025*64 = 3,148,800
    float* kp = qp + 3148800;
    float* vp = kp + 3148800;
    float* kt = vp + 3148800;                               // K transposed (b,12,64,1025)
    float* relH   = qkv_full;                               // 4*12*1024*32 = 1,572,864
    float* relW   = relH + 1572864;
    float* outpre = relW + 1572864;                         // 3,148,800 (fits in recycled region)

    // 1) QKV GEMM: (16388 x 768) @ (768 x 2304)
    gemm_f32<<<dim3(36, 257), 256, 0, stream>>>(x, wqkv, nullptr, qkv_full, 16388, 2304, 768);
    // 2) conv-pool + LayerNorm for q, k, v (+ K^T)
    pool_ln_kernel<<<dim3(1025, 3, 4), 256, 0, stream>>>(qkv_full, dwq, dwk, dwv,
                                                         gq, bq, gk, bk, gv, bv,
                                                         qp, kp, vp, kt);
    // 3) rel_h / rel_w tables
    rel_kernel<<<dim3(12288), 256, 0, stream>>>(qp, rph, rpw, relH, relW);
    // 4) attention (streaming softmax) + residual -> out_pre (b, tok, 768)
    attn_kernel<<<dim3(129, 48), 256, 0, stream>>>(qp, kt, vp, relH, relW, outpre);
    // 5) proj: (4100 x 768) @ (768 x 768) + bias
    gemm_f32<<<dim3(12, 65), 256, 0, stream>>>(outpre, wproj, bproj, out, 4100, 768, 768);
}

// Round 2
// 875.274 us; speedup vs baseline: 1.7791x; 1.7791x over previous
//
#include <hip/hip_runtime.h>
#include <hip/hip_bf16.h>
#include <cstddef>

// Problem constants
// B=4, H=W=64, DIM=768, HEADS=12, HD=64, STRIDE=2, N=4097, pooled tokens=1025
#define NTOK 4097
#define NPOOL 1025
#define DIMC 768

typedef short  s16x8 __attribute__((ext_vector_type(8)));
typedef float  f32x4 __attribute__((ext_vector_type(4)));
typedef unsigned short u16x8 __attribute__((ext_vector_type(8)));

static __device__ inline unsigned short f2bf(float x) {
    __hip_bfloat16 h = __float2bfloat16(x);
    return *reinterpret_cast<unsigned short*>(&h);
}

#define GLDS(gp, lp) __builtin_amdgcn_global_load_lds(                        \
    (const __attribute__((address_space(1))) void*)(gp),                      \
    (__attribute__((address_space(3))) void*)(lp), 16, 0, 0)

// ---------------------------------------------------------------------------
// Pad + convert f32 [rows_valid][768] -> bf16 [rows_pad][768] (pad rows zero).
// One thread = 8 elements (one 16B bf16 store).
// ---------------------------------------------------------------------------
__global__ __launch_bounds__(256) void cvt_pad(const float* __restrict__ in,
                                               unsigned short* __restrict__ out,
                                               int rows_valid, int groups) {
    const int g = blockIdx.x * 256 + threadIdx.x;
    if (g >= groups) return;
    const int row = g / 96, off = (g - row * 96) * 8;
    u16x8 o;
    if (row < rows_valid) {
        const float4 v0 = *(const float4*)(in + (size_t)row * DIMC + off);
        const float4 v1 = *(const float4*)(in + (size_t)row * DIMC + off + 4);
        o[0] = f2bf(v0.x); o[1] = f2bf(v0.y); o[2] = f2bf(v0.z); o[3] = f2bf(v0.w);
        o[4] = f2bf(v1.x); o[5] = f2bf(v1.y); o[6] = f2bf(v1.z); o[7] = f2bf(v1.w);
    } else {
        o = (u16x8){0, 0, 0, 0, 0, 0, 0, 0};
    }
    *(u16x8*)(out + (size_t)g * 8) = o;
}

// ---------------------------------------------------------------------------
// Transpose + convert: in f32 [R][C] -> out bf16 [C][R]. R,C % 32 == 0.
// ---------------------------------------------------------------------------
__global__ __launch_bounds__(256) void transpose_cvt(const float* __restrict__ in,
                                                     unsigned short* __restrict__ out,
                                                     int R, int C) {
    __shared__ float t[32][33];
    const int tx = threadIdx.x & 31, ty = threadIdx.x >> 5;   // ty 0..7
    const int r0 = blockIdx.y * 32, c0 = blockIdx.x * 32;
#pragma unroll
    for (int i = 0; i < 32; i += 8)
        t[ty + i][tx] = in[(size_t)(r0 + ty + i) * C + c0 + tx];
    __syncthreads();
#pragma unroll
    for (int i = 0; i < 32; i += 8)
        out[(size_t)(c0 + ty + i) * R + r0 + tx] = f2bf(t[tx][ty + i]);
}

// ---------------------------------------------------------------------------
// bf16 MFMA GEMM (m97 structure): C[M,N] = A[Mpad,K](bf16) @ Bt[N,K](bf16)^T.
// 128x128 tile, BK=32, 4 waves (2x2), each wave 4x4 fragments of 16x16x32.
// A must be padded to gridDim.y*128 rows; N % 128 == 0; K % 32 == 0.
// C stores guarded by row < M. Optional f32 bias per column.
// ---------------------------------------------------------------------------
__global__ __launch_bounds__(256) void gemm_bf16(const unsigned short* __restrict__ A,
                                                 const unsigned short* __restrict__ Bt,
                                                 const float* __restrict__ bias,
                                                 float* __restrict__ C,
                                                 int M, int N, int K) {
    __shared__ __align__(16) short As[128 * 32];
    __shared__ __align__(16) short Bs[128 * 32];
    const int tid = threadIdx.x;
    const int w = tid >> 6, lane = tid & 63;
    const int bm = blockIdx.y * 128, bn = blockIdx.x * 128;
    // staging coords: chunk c = 2w (+1); rows c*16 + (lane>>2), cols (lane&3)*8
    const int sr = lane >> 2, sc8 = (lane & 3) * 8;
    const unsigned short* aG = A + (size_t)(bm + w * 32 + sr) * K + sc8;
    const unsigned short* bG = Bt + (size_t)(bn + w * 32 + sr) * K + sc8;
    short* aL = As + w * 1024;
    short* bL = Bs + w * 1024;

    f32x4 acc[4][4];
#pragma unroll
    for (int m = 0; m < 4; ++m)
#pragma unroll
        for (int n = 0; n < 4; ++n) acc[m][n] = (f32x4){0.f, 0.f, 0.f, 0.f};

    const int wr = w >> 1, wc = w & 1;
    const int ar = wr * 64 + (lane & 15);
    const int br = wc * 64 + (lane & 15);
    const int ko = (lane >> 4) * 8;

    for (int k0 = 0; k0 < K; k0 += 32) {
        GLDS(aG, aL);
        GLDS(aG + 16 * (size_t)K, aL + 512);
        GLDS(bG, bL);
        GLDS(bG + 16 * (size_t)K, bL + 512);
        aG += 32; bG += 32;
        __syncthreads();
        s16x8 af[4], bf[4];
#pragma unroll
        for (int m = 0; m < 4; ++m)
            af[m] = *(const s16x8*)&As[(ar + m * 16) * 32 + ko];
#pragma unroll
        for (int n = 0; n < 4; ++n)
            bf[n] = *(const s16x8*)&Bs[(br + n * 16) * 32 + ko];
#pragma unroll
        for (int m = 0; m < 4; ++m)
#pragma unroll
            for (int n = 0; n < 4; ++n)
                acc[m][n] = __builtin_amdgcn_mfma_f32_16x16x32_bf16(af[m], bf[n], acc[m][n], 0, 0, 0);
        __syncthreads();
    }

    const int cr0 = bm + wr * 64 + (lane >> 4) * 4;
    const int cc0 = bn + wc * 64 + (lane & 15);
#pragma unroll
    for (int n = 0; n < 4; ++n) {
        const int col = cc0 + n * 16;
        const float bv = bias ? bias[col] : 0.f;
#pragma unroll
        for (int m = 0; m < 4; ++m) {
#pragma unroll
            for (int r = 0; r < 4; ++r) {
                const int row = cr0 + m * 16 + r;
                if (row < M) C[(size_t)row * N + col] = acc[m][n][r] + bv;
            }
        }
    }
}

// ---------------------------------------------------------------------------
// Pool: depthwise 3x3 stride-2 SAME conv on the head-shuffled grid view,
// then per-(head,token) LayerNorm over 64 channels (wave-local reduce).
// pos == 1024 handles the cls token (straight from qkv, LN only).
// Writes pooled (b,12,1025,64); for K also writes transposed (b,12,64,1025).
// ---------------------------------------------------------------------------
__global__ __launch_bounds__(256) void pool_ln_kernel(
    const float* __restrict__ qkv,
    const float* __restrict__ dwq, const float* __restrict__ dwk, const float* __restrict__ dwv,
    const float* __restrict__ gq, const float* __restrict__ bq,
    const float* __restrict__ gk, const float* __restrict__ bk,
    const float* __restrict__ gv, const float* __restrict__ bv,
    float* __restrict__ qp, float* __restrict__ kp, float* __restrict__ vp,
    float* __restrict__ kt) {
    const int pos = blockIdx.x;          // 0..1023 spatial, 1024 = cls
    const int which = blockIdx.y;        // 0=q,1=k,2=v
    const int bi = blockIdx.z;
    const float* w   = which == 0 ? dwq : which == 1 ? dwk : dwv;
    const float* gam = which == 0 ? gq  : which == 1 ? gk  : gv;
    const float* bet = which == 0 ? bq  : which == 1 ? bk  : bv;
    float* outp      = which == 0 ? qp  : which == 1 ? kp  : vp;
    const int wave = threadIdx.x >> 6, lane = threadIdx.x & 63;
    const size_t base = (size_t)bi * NTOK * 2304 + (size_t)which * DIMC;

    for (int db = wave; db < 12; db += 4) {
        float val;
        int h, tok;
        if (pos == 1024) {
            h = db; tok = 0;
            val = qkv[base + (size_t)db * 64 + lane];   // token 0 (cls)
        } else {
            const int oh = pos >> 5, ow = pos & 31;
            const int d = db * 64 + lane;
            float acc = 0.f;
#pragma unroll
            for (int kh = 0; kh < 3; ++kh) {
                const int ih = oh * 2 + kh;             // pad_lo = 0
#pragma unroll
                for (int kw = 0; kw < 3; ++kw) {
                    const int iw = ow * 2 + kw;
                    if (ih < 64 && iw < 64) {
                        const int m = (ih * 64 + iw) * DIMC + d;   // grid-flat offset
                        const int hin = m >> 18;                    // /262144
                        const int l   = (m >> 6) & 4095;
                        const int ci  = m & 63;
                        acc += qkv[base + (size_t)(1 + l) * 2304 + hin * 64 + ci]
                             * w[(kh * 3 + kw) * DIMC + d];
                    }
                }
            }
            val = acc;
            const int idx = pos * 12 + db;              // pooled 64-block index
            h = idx >> 10;
            tok = 1 + (idx & 1023);
        }
        // LayerNorm over 64 lanes (ci == lane)
        float s = val;
#pragma unroll
        for (int o = 32; o > 0; o >>= 1) s += __shfl_xor(s, o);
        const float mu = s * (1.f / 64.f);
        const float dv = val - mu;
        float s2 = dv * dv;
#pragma unroll
        for (int o = 32; o > 0; o >>= 1) s2 += __shfl_xor(s2, o);
        const float inv = rsqrtf(s2 * (1.f / 64.f) + 1e-3f);
        const float res = dv * inv * gam[lane] + bet[lane];
        outp[((size_t)(bi * 12 + h) * NPOOL + tok) * 64 + lane] = res;
        if (which == 1)
            kt[((size_t)(bi * 12 + h) * 64 + lane) * NPOOL + tok] = res;
    }
}

// ---------------------------------------------------------------------------
// rel tables: relH[b,y,qh,qw,kh] = sum_c qpool[b,y,tok,c]*rel_pos_h[qh-kh+31][c]
// One wave per q row; lanes 0..31 -> kh, 32..63 -> kw.
// ---------------------------------------------------------------------------
__global__ __launch_bounds__(256) void rel_kernel(const float* __restrict__ qp,
                                                  const float* __restrict__ rph,
                                                  const float* __restrict__ rpw,
                                                  float* __restrict__ relH,
                                                  float* __restrict__ relW) {
    __shared__ float qs[4][64];
    const int wave = threadIdx.x >> 6, lane = threadIdx.x & 63;
    const int r = blockIdx.x * 4 + wave;         // 0..49151 = (b*12+y)*1024+pos
    const int bh = r >> 10, pos = r & 1023;
    const int qh = pos >> 5, qw = pos & 31;
    qs[wave][lane] = qp[((size_t)bh * NPOOL + 1 + pos) * 64 + lane];
    __syncthreads();
    const int kj = lane & 31;
    const float* tab = (lane < 32) ? (rph + (qh - kj + 31) * 64)
                                   : (rpw + (qw - kj + 31) * 64);
    float acc = 0.f;
#pragma unroll
    for (int c = 0; c < 64; ++c) acc += qs[wave][c] * tab[c];
    if (lane < 32) relH[(size_t)r * 32 + kj] = acc;
    else           relW[(size_t)r * 32 + kj] = acc;
}

// ---------------------------------------------------------------------------
// Attention: per block = (b*12+h, 8 q-rows). Two-pass softmax with the 8x1025
// logit tile in LDS. rel_h/rel_w gathered per (q,k). PV + residual + write to
// out_pre in (b, tok, head*64+c) layout.
// ---------------------------------------------------------------------------
__global__ __launch_bounds__(256) void attn_kernel(
    const float* __restrict__ qp, const float* __restrict__ kt, const float* __restrict__ vp,
    const float* __restrict__ relH, const float* __restrict__ relW,
    float* __restrict__ outp) {
    __shared__ float logits[8][1028];
    __shared__ float qst[64][8];     // q transposed: [c][qi]
    __shared__ float srow[8];
    const int bh = blockIdx.y;       // 0..47
    const int bi = bh / 12, hh = bh % 12;
    const int q0 = blockIdx.x * 8;
    const int tid = threadIdx.x;

    for (int i = tid; i < 512; i += 256) {
        const int qi = i >> 6, c = i & 63;
        const int qr = q0 + qi;
        qst[c][qi] = (qr < NPOOL) ? qp[((size_t)bh * NPOOL + qr) * 64 + c] : 0.f;
    }
    __syncthreads();

    const float* KT = kt + (size_t)bh * 64 * NPOOL;
    for (int kc = 0; kc < NPOOL; kc += 256) {
        const int k = kc + tid;
        if (k < NPOOL) {
            float acc[8] = {0, 0, 0, 0, 0, 0, 0, 0};
            for (int c = 0; c < 64; ++c) {
                const float kv = KT[c * NPOOL + k];
                const float4 a0 = *(const float4*)&qst[c][0];
                const float4 a1 = *(const float4*)&qst[c][4];
                acc[0] += a0.x * kv; acc[1] += a0.y * kv;
                acc[2] += a0.z * kv; acc[3] += a0.w * kv;
                acc[4] += a1.x * kv; acc[5] += a1.y * kv;
                acc[6] += a1.z * kv; acc[7] += a1.w * kv;
            }
            const int kk = k - 1;
            const int kh = kk >> 5, kwj = kk & 31;
#pragma unroll
            for (int qi = 0; qi < 8; ++qi) {
                const int qr = q0 + qi;
                float v = acc[qi] * 0.125f;          // scale = HD^-0.5
                if (k >= 1 && qr >= 1 && qr < NPOOL) {
                    const size_t rb = ((size_t)bh * 1024 + (qr - 1)) * 32;
                    v += relH[rb + kh] + relW[rb + kwj];
                }
                logits[qi][k] = v;
            }
        }
    }
    __syncthreads();

    const int wave = tid >> 6, lane = tid & 63;
    for (int qi = wave; qi < 8; qi += 4) {
        if (q0 + qi >= NPOOL) break;                 // wave-uniform
        float m = -3.0e38f;
        for (int k = lane; k < NPOOL; k += 64) m = fmaxf(m, logits[qi][k]);
#pragma unroll
        for (int o = 32; o > 0; o >>= 1) m = fmaxf(m, __shfl_xor(m, o));
        float s = 0.f;
        for (int k = lane; k < NPOOL; k += 64) {
            const float p = __expf(logits[qi][k] - m);
            logits[qi][k] = p;
            s += p;
        }
#pragma unroll
        for (int o = 32; o > 0; o >>= 1) s += __shfl_xor(s, o);
        if (lane == 0) srow[qi] = s;
    }
    __syncthreads();

    const int c = tid & 63, g = tid >> 6;
    const float* V = vp + (size_t)bh * NPOOL * 64;
    float acc0 = 0.f, acc1 = 0.f;
    for (int k = 0; k < NPOOL; ++k) {
        const float vv = V[(size_t)k * 64 + c];
        acc0 += logits[g][k] * vv;
        acc1 += logits[g + 4][k] * vv;
    }
    {
        const int qr = q0 + g;
        if (qr < NPOOL) {
            const float o = acc0 / srow[g] + qst[c][g];
            outp[((size_t)bi * NPOOL + qr) * DIMC + hh * 64 + c] = o;
        }
        const int qr2 = q0 + g + 4;
        if (qr2 < NPOOL) {
            const float o = acc1 / srow[g + 4] + qst[c][g + 4];
            outp[((size_t)bi * NPOOL + qr2) * DIMC + hh * 64 + c] = o;
        }
    }
}

// ---------------------------------------------------------------------------
extern "C" void kernel_launch(void* const* d_in, const int* in_sizes, int n_in,
                              void* d_out, int out_size, void* d_ws, size_t ws_size,
                              hipStream_t stream) {
    const float* x     = (const float*)d_in[0];
    const float* wqkv  = (const float*)d_in[1];
    const float* dwq   = (const float*)d_in[2];
    const float* dwk   = (const float*)d_in[3];
    const float* dwv   = (const float*)d_in[4];
    const float* gq    = (const float*)d_in[5];
    const float* bq    = (const float*)d_in[6];
    const float* gk    = (const float*)d_in[7];
    const float* bk    = (const float*)d_in[8];
    const float* gv    = (const float*)d_in[9];
    const float* bv    = (const float*)d_in[10];
    const float* rph   = (const float*)d_in[11];
    const float* rpw   = (const float*)d_in[12];
    const float* wproj = (const float*)d_in[13];
    const float* bproj = (const float*)d_in[14];
    float* out = (float*)d_out;
    float* ws_f = (float*)d_ws;

    // Workspace layout (floats). qkv_full region recycled for rel/outpre/bf16
    // buffers once pooling has consumed it; qp..kt region hosts the bf16
    // staging buffers BEFORE pool_ln writes it.
    float* qkv_full = ws_f;                                 // 16388*2304 = 37,757,952
    float* qp = ws_f + 37757952;                            // 4*12*1025*64 = 3,148,800
    float* kp = qp + 3148800;
    float* vp = kp + 3148800;
    float* kt = vp + 3148800;                               // K transposed (b,12,64,1025)
    unsigned short* x_bf    = (unsigned short*)qp;          // 16512*768 u16 (dead before pool)
    unsigned short* wqkv_bf = (unsigned short*)kt;          // 2304*768 u16 (dead before pool)
    float* relH   = qkv_full;                               // 4*12*1024*32 = 1,572,864
    float* relW   = relH + 1572864;
    float* outpre = relW + 1572864;                         // 4100*768 = 3,148,800
    unsigned short* outpre_bf = (unsigned short*)(outpre + 3148800);   // 4224*768 u16
    unsigned short* wproj_bf  = (unsigned short*)(outpre + 3148800 + 1622016); // 768*768 u16

    // 1) convert + pad A, transpose + convert B for the qkv GEMM
    cvt_pad<<<(16512 * 96 + 255) / 256, 256, 0, stream>>>(x, x_bf, 16388, 16512 * 96);
    transpose_cvt<<<dim3(2304 / 32, 768 / 32), 256, 0, stream>>>(wqkv, wqkv_bf, 768, 2304);
    // 2) QKV GEMM (bf16 MFMA): (16388 x 768) @ (768 x 2304)
    gemm_bf16<<<dim3(18, 129), 256, 0, stream>>>(x_bf, wqkv_bf, nullptr, qkv_full, 16388, 2304, 768);
    // 3) conv-pool + LayerNorm for q, k, v (+ K^T)
    pool_ln_kernel<<<dim3(1025, 3, 4), 256, 0, stream>>>(qkv_full, dwq, dwk, dwv,
                                                         gq, bq, gk, bk, gv, bv,
                                                         qp, kp, vp, kt);
    // 4) rel_h / rel_w tables
    rel_kernel<<<dim3(12288), 256, 0, stream>>>(qp, rph, rpw, relH, relW);
    // 5) attention (streaming softmax) + residual -> outpre (b, tok, 768)
    attn_kernel<<<dim3(129, 48), 256, 0, stream>>>(qp, kt, vp, relH, relW, outpre);
    // 6) proj GEMM (bf16 MFMA): (4100 x 768) @ (768 x 768) + bias
    cvt_pad<<<(4224 * 96 + 255) / 256, 256, 0, stream>>>(outpre, outpre_bf, 4100, 4224 * 96);
    transpose_cvt<<<dim3(768 / 32, 768 / 32), 256, 0, stream>>>(wproj, wproj_bf, 768, 768);
    gemm_bf16<<<dim3(6, 33), 256, 0, stream>>>(outpre_bf, wproj_bf, bproj, out, 4100, 768, 768);
}

// Round 3
// 489.824 us; speedup vs baseline: 3.1791x; 1.7869x over previous
//
#include <hip/hip_runtime.h>
#include <hip/hip_bf16.h>
#include <cstddef>

// Problem constants
// B=4, H=W=64, DIM=768, HEADS=12, HD=64, STRIDE=2, N=4097, pooled tokens=1025
#define NTOK 4097
#define NPOOL 1025
#define DIMC 768

typedef short  s16x8 __attribute__((ext_vector_type(8)));
typedef float  f32x4 __attribute__((ext_vector_type(4)));
typedef unsigned short u16x8 __attribute__((ext_vector_type(8)));

static __device__ inline unsigned short f2bf(float x) {
    __hip_bfloat16 h = __float2bfloat16(x);
    return *reinterpret_cast<unsigned short*>(&h);
}

#define GLDS(gp, lp) __builtin_amdgcn_global_load_lds(                        \
    (const __attribute__((address_space(1))) void*)(gp),                      \
    (__attribute__((address_space(3))) void*)(lp), 16, 0, 0)

// ---------------------------------------------------------------------------
// Pad + convert f32 [rows_valid][768] -> bf16 [rows_pad][768] (pad rows zero).
// ---------------------------------------------------------------------------
__global__ __launch_bounds__(256) void cvt_pad(const float* __restrict__ in,
                                               unsigned short* __restrict__ out,
                                               int rows_valid, int groups) {
    const int g = blockIdx.x * 256 + threadIdx.x;
    if (g >= groups) return;
    const int row = g / 96, off = (g - row * 96) * 8;
    u16x8 o;
    if (row < rows_valid) {
        const float4 v0 = *(const float4*)(in + (size_t)row * DIMC + off);
        const float4 v1 = *(const float4*)(in + (size_t)row * DIMC + off + 4);
        o[0] = f2bf(v0.x); o[1] = f2bf(v0.y); o[2] = f2bf(v0.z); o[3] = f2bf(v0.w);
        o[4] = f2bf(v1.x); o[5] = f2bf(v1.y); o[6] = f2bf(v1.z); o[7] = f2bf(v1.w);
    } else {
        o = (u16x8){0, 0, 0, 0, 0, 0, 0, 0};
    }
    *(u16x8*)(out + (size_t)g * 8) = o;
}

// ---------------------------------------------------------------------------
// Transpose + convert: in f32 [R][C] -> out bf16 [C][R]. R,C % 32 == 0.
// ---------------------------------------------------------------------------
__global__ __launch_bounds__(256) void transpose_cvt(const float* __restrict__ in,
                                                     unsigned short* __restrict__ out,
                                                     int R, int C) {
    __shared__ float t[32][33];
    const int tx = threadIdx.x & 31, ty = threadIdx.x >> 5;   // ty 0..7
    const int r0 = blockIdx.y * 32, c0 = blockIdx.x * 32;
#pragma unroll
    for (int i = 0; i < 32; i += 8)
        t[ty + i][tx] = in[(size_t)(r0 + ty + i) * C + c0 + tx];
    __syncthreads();
#pragma unroll
    for (int i = 0; i < 32; i += 8)
        out[(size_t)(c0 + ty + i) * R + r0 + tx] = f2bf(t[tx][ty + i]);
}

// ---------------------------------------------------------------------------
// bf16 MFMA GEMM (m97 structure): C[M,N] = A[Mpad,K](bf16) @ Bt[N,K](bf16)^T.
// 128x128 tile, BK=32, 4 waves (2x2), each wave 4x4 fragments of 16x16x32.
// ---------------------------------------------------------------------------
__global__ __launch_bounds__(256) void gemm_bf16(const unsigned short* __restrict__ A,
                                                 const unsigned short* __restrict__ Bt,
                                                 const float* __restrict__ bias,
                                                 float* __restrict__ C,
                                                 int M, int N, int K) {
    __shared__ __align__(16) short As[128 * 32];
    __shared__ __align__(16) short Bs[128 * 32];
    const int tid = threadIdx.x;
    const int w = tid >> 6, lane = tid & 63;
    const int bm = blockIdx.y * 128, bn = blockIdx.x * 128;
    const int sr = lane >> 2, sc8 = (lane & 3) * 8;
    const unsigned short* aG = A + (size_t)(bm + w * 32 + sr) * K + sc8;
    const unsigned short* bG = Bt + (size_t)(bn + w * 32 + sr) * K + sc8;
    short* aL = As + w * 1024;
    short* bL = Bs + w * 1024;

    f32x4 acc[4][4];
#pragma unroll
    for (int m = 0; m < 4; ++m)
#pragma unroll
        for (int n = 0; n < 4; ++n) acc[m][n] = (f32x4){0.f, 0.f, 0.f, 0.f};

    const int wr = w >> 1, wc = w & 1;
    const int ar = wr * 64 + (lane & 15);
    const int br = wc * 64 + (lane & 15);
    const int ko = (lane >> 4) * 8;

    for (int k0 = 0; k0 < K; k0 += 32) {
        GLDS(aG, aL);
        GLDS(aG + 16 * (size_t)K, aL + 512);
        GLDS(bG, bL);
        GLDS(bG + 16 * (size_t)K, bL + 512);
        aG += 32; bG += 32;
        __syncthreads();
        s16x8 af[4], bf[4];
#pragma unroll
        for (int m = 0; m < 4; ++m)
            af[m] = *(const s16x8*)&As[(ar + m * 16) * 32 + ko];
#pragma unroll
        for (int n = 0; n < 4; ++n)
            bf[n] = *(const s16x8*)&Bs[(br + n * 16) * 32 + ko];
#pragma unroll
        for (int m = 0; m < 4; ++m)
#pragma unroll
            for (int n = 0; n < 4; ++n)
                acc[m][n] = __builtin_amdgcn_mfma_f32_16x16x32_bf16(af[m], bf[n], acc[m][n], 0, 0, 0);
        __syncthreads();
    }

    const int cr0 = bm + wr * 64 + (lane >> 4) * 4;
    const int cc0 = bn + wc * 64 + (lane & 15);
#pragma unroll
    for (int n = 0; n < 4; ++n) {
        const int col = cc0 + n * 16;
        const float bv = bias ? bias[col] : 0.f;
#pragma unroll
        for (int m = 0; m < 4; ++m) {
#pragma unroll
            for (int r = 0; r < 4; ++r) {
                const int row = cr0 + m * 16 + r;
                if (row < M) C[(size_t)row * N + col] = acc[m][n][r] + bv;
            }
        }
    }
}

// ---------------------------------------------------------------------------
// Pool: depthwise 3x3 stride-2 SAME conv on the head-shuffled grid view,
// then per-(head,token) LayerNorm over 64 channels (wave-local reduce).
// which==0 -> qp f32 + qp_bf ; which==1 -> kp_bf ; which==2 -> vt_bf (transposed)
// ---------------------------------------------------------------------------
__global__ __launch_bounds__(256) void pool_ln_kernel(
    const float* __restrict__ qkv,
    const float* __restrict__ dwq, const float* __restrict__ dwk, const float* __restrict__ dwv,
    const float* __restrict__ gq, const float* __restrict__ bq,
    const float* __restrict__ gk, const float* __restrict__ bk,
    const float* __restrict__ gv, const float* __restrict__ bv,
    float* __restrict__ qp, unsigned short* __restrict__ qbf,
    unsigned short* __restrict__ kbf, unsigned short* __restrict__ vtbf) {
    const int pos = blockIdx.x;          // 0..1023 spatial, 1024 = cls
    const int which = blockIdx.y;        // 0=q,1=k,2=v
    const int bi = blockIdx.z;
    const float* w   = which == 0 ? dwq : which == 1 ? dwk : dwv;
    const float* gam = which == 0 ? gq  : which == 1 ? gk  : gv;
    const float* bet = which == 0 ? bq  : which == 1 ? bk  : bv;
    const int wave = threadIdx.x >> 6, lane = threadIdx.x & 63;
    const size_t base = (size_t)bi * NTOK * 2304 + (size_t)which * DIMC;

    for (int db = wave; db < 12; db += 4) {
        float val;
        int h, tok;
        if (pos == 1024) {
            h = db; tok = 0;
            val = qkv[base + (size_t)db * 64 + lane];   // token 0 (cls)
        } else {
            const int oh = pos >> 5, ow = pos & 31;
            const int d = db * 64 + lane;
            float acc = 0.f;
#pragma unroll
            for (int kh = 0; kh < 3; ++kh) {
                const int ih = oh * 2 + kh;             // pad_lo = 0
#pragma unroll
                for (int kw = 0; kw < 3; ++kw) {
                    const int iw = ow * 2 + kw;
                    if (ih < 64 && iw < 64) {
                        const int m = (ih * 64 + iw) * DIMC + d;   // grid-flat offset
                        const int hin = m >> 18;
                        const int l   = (m >> 6) & 4095;
                        const int ci  = m & 63;
                        acc += qkv[base + (size_t)(1 + l) * 2304 + hin * 64 + ci]
                             * w[(kh * 3 + kw) * DIMC + d];
                    }
                }
            }
            val = acc;
            const int idx = pos * 12 + db;
            h = idx >> 10;
            tok = 1 + (idx & 1023);
        }
        // LayerNorm over 64 lanes
        float s = val;
#pragma unroll
        for (int o = 32; o > 0; o >>= 1) s += __shfl_xor(s, o);
        const float mu = s * (1.f / 64.f);
        const float dv = val - mu;
        float s2 = dv * dv;
#pragma unroll
        for (int o = 32; o > 0; o >>= 1) s2 += __shfl_xor(s2, o);
        const float inv = rsqrtf(s2 * (1.f / 64.f) + 1e-3f);
        const float res = dv * inv * gam[lane] + bet[lane];
        const size_t bh = (size_t)(bi * 12 + h);
        if (which == 0) {
            qp[(bh * NPOOL + tok) * 64 + lane] = res;
            qbf[(bh * 1040 + tok) * 64 + lane] = f2bf(res);
        } else if (which == 1) {
            kbf[(bh * 1056 + tok) * 64 + lane] = f2bf(res);
        } else {
            vtbf[(bh * 64 + lane) * 1056 + tok] = f2bf(res);
        }
    }
}

// ---------------------------------------------------------------------------
// rel tables: relH[b,y,pos,kh] = sum_c qpool[b,y,1+pos,c]*rel_pos_h[qh-kh+31][c]
// ---------------------------------------------------------------------------
__global__ __launch_bounds__(256) void rel_kernel(const float* __restrict__ qp,
                                                  const float* __restrict__ rph,
                                                  const float* __restrict__ rpw,
                                                  float* __restrict__ relH,
                                                  float* __restrict__ relW) {
    __shared__ float qs[4][64];
    const int wave = threadIdx.x >> 6, lane = threadIdx.x & 63;
    const int r = blockIdx.x * 4 + wave;
    const int bh = r >> 10, pos = r & 1023;
    const int qh = pos >> 5, qw = pos & 31;
    qs[wave][lane] = qp[((size_t)bh * NPOOL + 1 + pos) * 64 + lane];
    __syncthreads();
    const int kj = lane & 31;
    const float* tab = (lane < 32) ? (rph + (qh - kj + 31) * 64)
                                   : (rpw + (qw - kj + 31) * 64);
    float acc = 0.f;
#pragma unroll
    for (int c = 0; c < 64; ++c) acc += qs[wave][c] * tab[c];
    if (lane < 32) relH[(size_t)r * 32 + kj] = acc;
    else           relW[(size_t)r * 32 + kj] = acc;
}

// ---------------------------------------------------------------------------
// MFMA attention. Block = (bh, 16 q-rows), 4 waves.
// Pass1: waves split 66 k-tiles; S = QK^T via mfma + rel bias -> LDS logits.
// Pass2: wave-parallel row softmax. Pass3: PV via mfma (P cvt from LDS),
// /rowsum + residual -> outpre (b, tok, 768).
// ---------------------------------------------------------------------------
#define LSTR 1060
__global__ __launch_bounds__(256) void attn_mfma(
    const unsigned short* __restrict__ qbf, const unsigned short* __restrict__ kbf,
    const unsigned short* __restrict__ vtbf, const float* __restrict__ qpf,
    const float* __restrict__ relH, const float* __restrict__ relW,
    float* __restrict__ outp) {
    __shared__ float logits_s[16 * LSTR];
    __shared__ float relh_s[16][32];
    __shared__ float relw_s[16][32];
    __shared__ float srow_s[16];
    const int bh = blockIdx.y, bi = bh / 12, hh = bh % 12;
    const int q0 = blockIdx.x * 16;
    const int tid = threadIdx.x, w = tid >> 6, lane = tid & 63;

    // rel rows for this q-tile into LDS
    for (int i = tid; i < 512; i += 256) {
        const int qi = i >> 5, j = i & 31;
        const int qg = q0 + qi;
        float rh = 0.f, rw = 0.f;
        if (qg >= 1 && qg < NPOOL) {
            const size_t rb = ((size_t)bh * 1024 + (qg - 1)) * 32;
            rh = relH[rb + j]; rw = relW[rb + j];
        }
        relh_s[qi][j] = rh; relw_s[qi][j] = rw;
    }

    const int frow = lane & 15, fcol = (lane >> 4) * 8;
    const unsigned short* qrow_p = qbf + ((size_t)bh * 1040 + q0 + frow) * 64 + fcol;
    s16x8 aq0 = *(const s16x8*)qrow_p;
    s16x8 aq1 = *(const s16x8*)(qrow_p + 32);
    __syncthreads();

    // ---- pass 1: logits ----
    for (int t = w; t < 66; t += 4) {
        const int k0 = t * 16;
        const unsigned short* kb = kbf + ((size_t)bh * 1056 + k0 + frow) * 64 + fcol;
        s16x8 b0 = *(const s16x8*)kb;
        s16x8 b1 = *(const s16x8*)(kb + 32);
        f32x4 s = (f32x4){0.f, 0.f, 0.f, 0.f};
        s = __builtin_amdgcn_mfma_f32_16x16x32_bf16(aq0, b0, s, 0, 0, 0);
        s = __builtin_amdgcn_mfma_f32_16x16x32_bf16(aq1, b1, s, 0, 0, 0);
        const int kcol = k0 + frow;
        const int qrow0 = (lane >> 4) * 4;
#pragma unroll
        for (int r = 0; r < 4; ++r) {
            const int qrow = qrow0 + r, qg = q0 + qrow;
            float v;
            if (kcol >= NPOOL) {
                v = -3.0e38f;
            } else {
                v = s[r] * 0.125f;
                if (kcol >= 1 && qg >= 1)
                    v += relh_s[qrow][(kcol - 1) >> 5] + relw_s[qrow][(kcol - 1) & 31];
            }
            logits_s[qrow * LSTR + kcol] = v;
        }
    }
    __syncthreads();

    // ---- pass 2: softmax ----
    for (int qi = w; qi < 16; qi += 4) {
        float m = -3.0e38f;
        for (int k = lane; k < 1056; k += 64) m = fmaxf(m, logits_s[qi * LSTR + k]);
#pragma unroll
        for (int o = 32; o > 0; o >>= 1) m = fmaxf(m, __shfl_xor(m, o));
        float sum = 0.f;
        for (int k = lane; k < 1056; k += 64) {
            const float p = __expf(logits_s[qi * LSTR + k] - m);
            logits_s[qi * LSTR + k] = p;
            sum += p;
        }
#pragma unroll
        for (int o = 32; o > 0; o >>= 1) sum += __shfl_xor(sum, o);
        if (lane == 0) srow_s[qi] = sum;
    }
    __syncthreads();

    // ---- pass 3: PV ----
    const unsigned short* vrow = vtbf + ((size_t)bh * 64 + w * 16 + frow) * 1056 + fcol;
    f32x4 acc = (f32x4){0.f, 0.f, 0.f, 0.f};
    for (int c = 0; c < 33; ++c) {
        const float* pp = &logits_s[frow * LSTR + c * 32 + fcol];
        f32x4 p0 = *(const f32x4*)pp;
        f32x4 p1 = *(const f32x4*)(pp + 4);
        s16x8 pa;
        pa[0] = (short)f2bf(p0[0]); pa[1] = (short)f2bf(p0[1]);
        pa[2] = (short)f2bf(p0[2]); pa[3] = (short)f2bf(p0[3]);
        pa[4] = (short)f2bf(p1[0]); pa[5] = (short)f2bf(p1[1]);
        pa[6] = (short)f2bf(p1[2]); pa[7] = (short)f2bf(p1[3]);
        s16x8 vb = *(const s16x8*)(vrow + c * 32);
        acc = __builtin_amdgcn_mfma_f32_16x16x32_bf16(pa, vb, acc, 0, 0, 0);
    }
#pragma unroll
    for (int r = 0; r < 4; ++r) {
        const int qrow = (lane >> 4) * 4 + r, qg = q0 + qrow;
        if (qg < NPOOL) {
            const int d = w * 16 + frow;
            const float o = acc[r] / srow_s[qrow]
                          + qpf[((size_t)bh * NPOOL + qg) * 64 + d];
            outp[((size_t)bi * NPOOL + qg) * DIMC + hh * 64 + d] = o;
        }
    }
}

// ---------------------------------------------------------------------------
extern "C" void kernel_launch(void* const* d_in, const int* in_sizes, int n_in,
                              void* d_out, int out_size, void* d_ws, size_t ws_size,
                              hipStream_t stream) {
    const float* x     = (const float*)d_in[0];
    const float* wqkv  = (const float*)d_in[1];
    const float* dwq   = (const float*)d_in[2];
    const float* dwk   = (const float*)d_in[3];
    const float* dwv   = (const float*)d_in[4];
    const float* gq    = (const float*)d_in[5];
    const float* bq    = (const float*)d_in[6];
    const float* gk    = (const float*)d_in[7];
    const float* bk    = (const float*)d_in[8];
    const float* gv    = (const float*)d_in[9];
    const float* bv    = (const float*)d_in[10];
    const float* rph   = (const float*)d_in[11];
    const float* rpw   = (const float*)d_in[12];
    const float* wproj = (const float*)d_in[13];
    const float* bproj = (const float*)d_in[14];
    float* out = (float*)d_out;
    float* ws_f = (float*)d_ws;

    // Workspace layout (f32 units):
    //   [0, 37,757,952)              qkv_full; recycled after pool for
    //                                relH/relW/outpre/outpre_bf/wproj_bf
    //   A = 37,757,952:
    //     qp    f32  A+0         (3,148,800)
    //     qp_bf u16  A+3,148,800 (1,597,440 f32-eq)  48 x 1040 x 64
    //     kp_bf u16  A+4,746,240 (1,622,016 f32-eq)  48 x 1056 x 64
    //     vt_bf u16  A+6,368,256 (1,622,016 f32-eq)  48 x 64 x 1056
    //     wqkv_bf u16 A+7,990,272 (884,736 f32-eq)
    //   x_bf u16 @ A (6,340,608 f32-eq) - dead after gemm1; pool overwrites.
    const size_t A = 37757952;
    float* qkv_full = ws_f;
    float* qp = ws_f + A;
    unsigned short* qp_bf = (unsigned short*)(ws_f + A + 3148800);
    unsigned short* kp_bf = (unsigned short*)(ws_f + A + 4746240);
    unsigned short* vt_bf = (unsigned short*)(ws_f + A + 6368256);
    unsigned short* wqkv_bf = (unsigned short*)(ws_f + A + 7990272);
    unsigned short* x_bf = (unsigned short*)qp;
    float* relH   = ws_f;
    float* relW   = ws_f + 1572864;
    float* outpre = ws_f + 3145728;
    unsigned short* outpre_bf = (unsigned short*)(ws_f + 6294528);
    unsigned short* wproj_bf  = (unsigned short*)(ws_f + 7916544);

    // 0) zero V^T pad columns (whole buffer, 6.5 MB)
    hipMemsetAsync(vt_bf, 0, (size_t)48 * 64 * 1056 * 2, stream);
    // 1) convert + pad A, transpose + convert B for the qkv GEMM
    cvt_pad<<<(16512 * 96 + 255) / 256, 256, 0, stream>>>(x, x_bf, 16388, 16512 * 96);
    transpose_cvt<<<dim3(2304 / 32, 768 / 32), 256, 0, stream>>>(wqkv, wqkv_bf, 768, 2304);
    // 2) QKV GEMM (bf16 MFMA): (16388 x 768) @ (768 x 2304)
    gemm_bf16<<<dim3(18, 129), 256, 0, stream>>>(x_bf, wqkv_bf, nullptr, qkv_full, 16388, 2304, 768);
    // 3) conv-pool + LayerNorm -> qp f32, qp/kp bf16, V^T bf16
    pool_ln_kernel<<<dim3(1025, 3, 4), 256, 0, stream>>>(qkv_full, dwq, dwk, dwv,
                                                         gq, bq, gk, bk, gv, bv,
                                                         qp, qp_bf, kp_bf, vt_bf);
    // 4) rel_h / rel_w tables
    rel_kernel<<<dim3(12288), 256, 0, stream>>>(qp, rph, rpw, relH, relW);
    // 5) MFMA attention + residual -> outpre (b, tok, 768)
    attn_mfma<<<dim3(65, 48), 256, 0, stream>>>(qp_bf, kp_bf, vt_bf, qp, relH, relW, outpre);
    // 6) proj GEMM (bf16 MFMA): (4100 x 768) @ (768 x 768) + bias
    cvt_pad<<<(4224 * 96 + 255) / 256, 256, 0, stream>>>(outpre, outpre_bf, 4100, 4224 * 96);
    transpose_cvt<<<dim3(768 / 32, 768 / 32), 256, 0, stream>>>(wproj, wproj_bf, 768, 768);
    gemm_bf16<<<dim3(6, 33), 256, 0, stream>>>(outpre_bf, wproj_bf, bproj, out, 4100, 768, 768);
}

// Round 4
// 486.793 us; speedup vs baseline: 3.1989x; 1.0062x over previous
//
#include <hip/hip_runtime.h>
#include <hip/hip_bf16.h>
#include <cstddef>

// Problem constants
// B=4, H=W=64, DIM=768, HEADS=12, HD=64, STRIDE=2, N=4097, pooled tokens=1025
#define NTOK 4097
#define NPOOL 1025
#define DIMC 768

typedef short  s16x8 __attribute__((ext_vector_type(8)));
typedef float  f32x4 __attribute__((ext_vector_type(4)));
typedef unsigned short u16x8 __attribute__((ext_vector_type(8)));

static __device__ inline unsigned short f2bf(float x) {
    __hip_bfloat16 h = __float2bfloat16(x);
    return *reinterpret_cast<unsigned short*>(&h);
}
static __device__ inline float bf2f(unsigned short u) {
    __hip_bfloat16 h;
    *reinterpret_cast<unsigned short*>(&h) = u;
    return __bfloat162float(h);
}

#define GLDS(gp, lp) __builtin_amdgcn_global_load_lds(                        \
    (const __attribute__((address_space(1))) void*)(gp),                      \
    (__attribute__((address_space(3))) void*)(lp), 16, 0, 0)

// ---------------------------------------------------------------------------
// Pad + convert f32 [rows_valid][768] -> bf16 [rows_pad][768] (pad rows zero).
// ---------------------------------------------------------------------------
__global__ __launch_bounds__(256) void cvt_pad(const float* __restrict__ in,
                                               unsigned short* __restrict__ out,
                                               int rows_valid, int groups) {
    const int g = blockIdx.x * 256 + threadIdx.x;
    if (g >= groups) return;
    const int row = g / 96, off = (g - row * 96) * 8;
    u16x8 o;
    if (row < rows_valid) {
        const float4 v0 = *(const float4*)(in + (size_t)row * DIMC + off);
        const float4 v1 = *(const float4*)(in + (size_t)row * DIMC + off + 4);
        o[0] = f2bf(v0.x); o[1] = f2bf(v0.y); o[2] = f2bf(v0.z); o[3] = f2bf(v0.w);
        o[4] = f2bf(v1.x); o[5] = f2bf(v1.y); o[6] = f2bf(v1.z); o[7] = f2bf(v1.w);
    } else {
        o = (u16x8){0, 0, 0, 0, 0, 0, 0, 0};
    }
    *(u16x8*)(out + (size_t)g * 8) = o;
}

// ---------------------------------------------------------------------------
// Transpose + convert: in f32 [R][C] -> out bf16 [C][R]. R,C % 32 == 0.
// ---------------------------------------------------------------------------
__global__ __launch_bounds__(256) void transpose_cvt(const float* __restrict__ in,
                                                     unsigned short* __restrict__ out,
                                                     int R, int C) {
    __shared__ float t[32][33];
    const int tx = threadIdx.x & 31, ty = threadIdx.x >> 5;   // ty 0..7
    const int r0 = blockIdx.y * 32, c0 = blockIdx.x * 32;
#pragma unroll
    for (int i = 0; i < 32; i += 8)
        t[ty + i][tx] = in[(size_t)(r0 + ty + i) * C + c0 + tx];
    __syncthreads();
#pragma unroll
    for (int i = 0; i < 32; i += 8)
        out[(size_t)(c0 + ty + i) * R + r0 + tx] = f2bf(t[tx][ty + i]);
}

// ---------------------------------------------------------------------------
// bf16 MFMA GEMM (m97 structure): C = A[Mpad,K](bf16) @ Bt[N,K](bf16)^T.
// 128x128 tile, BK=32, 4 waves (2x2), each wave 4x4 fragments of 16x16x32.
// out_bf: 1 -> store bf16 (u16), 0 -> store f32 (+bias).
// ---------------------------------------------------------------------------
__global__ __launch_bounds__(256) void gemm_bf16(const unsigned short* __restrict__ A,
                                                 const unsigned short* __restrict__ Bt,
                                                 const float* __restrict__ bias,
                                                 void* __restrict__ Cv,
                                                 int M, int N, int K, int out_bf) {
    __shared__ __align__(16) short As[128 * 32];
    __shared__ __align__(16) short Bs[128 * 32];
    const int tid = threadIdx.x;
    const int w = tid >> 6, lane = tid & 63;
    const int bm = blockIdx.y * 128, bn = blockIdx.x * 128;
    const int sr = lane >> 2, sc8 = (lane & 3) * 8;
    const unsigned short* aG = A + (size_t)(bm + w * 32 + sr) * K + sc8;
    const unsigned short* bG = Bt + (size_t)(bn + w * 32 + sr) * K + sc8;
    short* aL = As + w * 1024;
    short* bL = Bs + w * 1024;

    f32x4 acc[4][4];
#pragma unroll
    for (int m = 0; m < 4; ++m)
#pragma unroll
        for (int n = 0; n < 4; ++n) acc[m][n] = (f32x4){0.f, 0.f, 0.f, 0.f};

    const int wr = w >> 1, wc = w & 1;
    const int ar = wr * 64 + (lane & 15);
    const int br = wc * 64 + (lane & 15);
    const int ko = (lane >> 4) * 8;

    for (int k0 = 0; k0 < K; k0 += 32) {
        GLDS(aG, aL);
        GLDS(aG + 16 * (size_t)K, aL + 512);
        GLDS(bG, bL);
        GLDS(bG + 16 * (size_t)K, bL + 512);
        aG += 32; bG += 32;
        __syncthreads();
        s16x8 af[4], bf[4];
#pragma unroll
        for (int m = 0; m < 4; ++m)
            af[m] = *(const s16x8*)&As[(ar + m * 16) * 32 + ko];
#pragma unroll
        for (int n = 0; n < 4; ++n)
            bf[n] = *(const s16x8*)&Bs[(br + n * 16) * 32 + ko];
#pragma unroll
        for (int m = 0; m < 4; ++m)
#pragma unroll
            for (int n = 0; n < 4; ++n)
                acc[m][n] = __builtin_amdgcn_mfma_f32_16x16x32_bf16(af[m], bf[n], acc[m][n], 0, 0, 0);
        __syncthreads();
    }

    const int cr0 = bm + wr * 64 + (lane >> 4) * 4;
    const int cc0 = bn + wc * 64 + (lane & 15);
#pragma unroll
    for (int n = 0; n < 4; ++n) {
        const int col = cc0 + n * 16;
        const float bv = bias ? bias[col] : 0.f;
#pragma unroll
        for (int m = 0; m < 4; ++m) {
#pragma unroll
            for (int r = 0; r < 4; ++r) {
                const int row = cr0 + m * 16 + r;
                if (row < M) {
                    const float v = acc[m][n][r] + bv;
                    if (out_bf) ((unsigned short*)Cv)[(size_t)row * N + col] = f2bf(v);
                    else        ((float*)Cv)[(size_t)row * N + col] = v;
                }
            }
        }
    }
}

// ---------------------------------------------------------------------------
// Pool: depthwise 3x3 stride-2 SAME conv on the head-shuffled grid view (bf16
// qkv input), then per-(head,token) LayerNorm over 64 channels (wave reduce).
// which==0 -> qp f32 + qp_bf ; which==1 -> kp_bf ; which==2 -> vt_bf (transposed)
// ---------------------------------------------------------------------------
__global__ __launch_bounds__(256) void pool_ln_kernel(
    const unsigned short* __restrict__ qkv,
    const float* __restrict__ dwq, const float* __restrict__ dwk, const float* __restrict__ dwv,
    const float* __restrict__ gq, const float* __restrict__ bq,
    const float* __restrict__ gk, const float* __restrict__ bk,
    const float* __restrict__ gv, const float* __restrict__ bv,
    float* __restrict__ qp, unsigned short* __restrict__ qbf,
    unsigned short* __restrict__ kbf, unsigned short* __restrict__ vtbf) {
    const int pos = blockIdx.x;          // 0..1023 spatial, 1024 = cls
    const int which = blockIdx.y;        // 0=q,1=k,2=v
    const int bi = blockIdx.z;
    const float* w   = which == 0 ? dwq : which == 1 ? dwk : dwv;
    const float* gam = which == 0 ? gq  : which == 1 ? gk  : gv;
    const float* bet = which == 0 ? bq  : which == 1 ? bk  : bv;
    const int wave = threadIdx.x >> 6, lane = threadIdx.x & 63;
    const size_t base = (size_t)bi * NTOK * 2304 + (size_t)which * DIMC;

    for (int db = wave; db < 12; db += 4) {
        float val;
        int h, tok;
        if (pos == 1024) {
            h = db; tok = 0;
            val = bf2f(qkv[base + (size_t)db * 64 + lane]);
        } else {
            const int oh = pos >> 5, ow = pos & 31;
            const int d = db * 64 + lane;
            float acc = 0.f;
#pragma unroll
            for (int kh = 0; kh < 3; ++kh) {
                const int ih = oh * 2 + kh;             // pad_lo = 0
#pragma unroll
                for (int kw = 0; kw < 3; ++kw) {
                    const int iw = ow * 2 + kw;
                    if (ih < 64 && iw < 64) {
                        const int m = (ih * 64 + iw) * DIMC + d;   // grid-flat offset
                        const int hin = m >> 18;
                        const int l   = (m >> 6) & 4095;
                        const int ci  = m & 63;
                        acc += bf2f(qkv[base + (size_t)(1 + l) * 2304 + hin * 64 + ci])
                             * w[(kh * 3 + kw) * DIMC + d];
                    }
                }
            }
            val = acc;
            const int idx = pos * 12 + db;
            h = idx >> 10;
            tok = 1 + (idx & 1023);
        }
        // LayerNorm over 64 lanes
        float s = val;
#pragma unroll
        for (int o = 32; o > 0; o >>= 1) s += __shfl_xor(s, o);
        const float mu = s * (1.f / 64.f);
        const float dv = val - mu;
        float s2 = dv * dv;
#pragma unroll
        for (int o = 32; o > 0; o >>= 1) s2 += __shfl_xor(s2, o);
        const float inv = rsqrtf(s2 * (1.f / 64.f) + 1e-3f);
        const float res = dv * inv * gam[lane] + bet[lane];
        const size_t bh = (size_t)(bi * 12 + h);
        if (which == 0) {
            qp[(bh * NPOOL + tok) * 64 + lane] = res;
            qbf[(bh * 1040 + tok) * 64 + lane] = f2bf(res);
        } else if (which == 1) {
            kbf[(bh * 1056 + tok) * 64 + lane] = f2bf(res);
        } else {
            vtbf[(bh * 64 + lane) * 1056 + tok] = f2bf(res);
        }
    }
}

// ---------------------------------------------------------------------------
// rel tables: relH[b,y,pos,kh] = sum_c qpool[b,y,1+pos,c]*rel_pos_h[qh-kh+31][c]
// ---------------------------------------------------------------------------
__global__ __launch_bounds__(256) void rel_kernel(const float* __restrict__ qp,
                                                  const float* __restrict__ rph,
                                                  const float* __restrict__ rpw,
                                                  float* __restrict__ relH,
                                                  float* __restrict__ relW) {
    __shared__ float qs[4][64];
    const int wave = threadIdx.x >> 6, lane = threadIdx.x & 63;
    const int r = blockIdx.x * 4 + wave;
    const int bh = r >> 10, pos = r & 1023;
    const int qh = pos >> 5, qw = pos & 31;
    qs[wave][lane] = qp[((size_t)bh * NPOOL + 1 + pos) * 64 + lane];
    __syncthreads();
    const int kj = lane & 31;
    const float* tab = (lane < 32) ? (rph + (qh - kj + 31) * 64)
                                   : (rpw + (qw - kj + 31) * 64);
    float acc = 0.f;
#pragma unroll
    for (int c = 0; c < 64; ++c) acc += qs[wave][c] * tab[c];
    if (lane < 32) relH[(size_t)r * 32 + kj] = acc;
    else           relW[(size_t)r * 32 + kj] = acc;
}

// ---------------------------------------------------------------------------
// MFMA attention, 8 waves. Block = (bh, 16 q-rows).
// Pass1: waves split 66 k-tiles; S = QK^T via mfma + rel bias -> LDS logits.
// Pass2: wave-parallel row softmax (2 rows/wave).
// Pass3: PV via mfma, split over (4 d-frags) x (2 k-halves); k-half-1 partials
// combined through LDS; /rowsum + residual -> outpre (b, tok, 768).
// ---------------------------------------------------------------------------
#define LSTR 1060
__global__ __launch_bounds__(512) void attn_mfma(
    const unsigned short* __restrict__ qbf, const unsigned short* __restrict__ kbf,
    const unsigned short* __restrict__ vtbf, const float* __restrict__ qpf,
    const float* __restrict__ relH, const float* __restrict__ relW,
    float* __restrict__ outp) {
    __shared__ float logits_s[16 * LSTR];
    __shared__ float relh_s[16][32];
    __shared__ float relw_s[16][32];
    __shared__ float partial_s[4][16][17];
    __shared__ float srow_s[16];
    const int bh = blockIdx.y, bi = bh / 12, hh = bh % 12;
    const int q0 = blockIdx.x * 16;
    const int tid = threadIdx.x, w = tid >> 6, lane = tid & 63;

    // rel rows for this q-tile into LDS (512 threads -> one element each)
    {
        const int qi = tid >> 5, j = tid & 31;
        const int qg = q0 + qi;
        float rh = 0.f, rw = 0.f;
        if (qg >= 1 && qg < NPOOL) {
            const size_t rb = ((size_t)bh * 1024 + (qg - 1)) * 32;
            rh = relH[rb + j]; rw = relW[rb + j];
        }
        relh_s[qi][j] = rh; relw_s[qi][j] = rw;
    }

    const int frow = lane & 15, fcol = (lane >> 4) * 8;
    const unsigned short* qrow_p = qbf + ((size_t)bh * 1040 + q0 + frow) * 64 + fcol;
    s16x8 aq0 = *(const s16x8*)qrow_p;
    s16x8 aq1 = *(const s16x8*)(qrow_p + 32);
    __syncthreads();

    // ---- pass 1: logits ----
    for (int t = w; t < 66; t += 8) {
        const int k0 = t * 16;
        const unsigned short* kb = kbf + ((size_t)bh * 1056 + k0 + frow) * 64 + fcol;
        s16x8 b0 = *(const s16x8*)kb;
        s16x8 b1 = *(const s16x8*)(kb + 32);
        f32x4 s = (f32x4){0.f, 0.f, 0.f, 0.f};
        s = __builtin_amdgcn_mfma_f32_16x16x32_bf16(aq0, b0, s, 0, 0, 0);
        s = __builtin_amdgcn_mfma_f32_16x16x32_bf16(aq1, b1, s, 0, 0, 0);
        const int kcol = k0 + frow;
        const int qrow0 = (lane >> 4) * 4;
#pragma unroll
        for (int r = 0; r < 4; ++r) {
            const int qrow = qrow0 + r, qg = q0 + qrow;
            float v;
            if (kcol >= NPOOL) {
                v = -3.0e38f;
            } else {
                v = s[r] * 0.125f;
                if (kcol >= 1 && qg >= 1)
                    v += relh_s[qrow][(kcol - 1) >> 5] + relw_s[qrow][(kcol - 1) & 31];
            }
            logits_s[qrow * LSTR + kcol] = v;
        }
    }
    __syncthreads();

    // ---- pass 2: softmax (2 rows/wave) ----
    for (int qi = w; qi < 16; qi += 8) {
        float m = -3.0e38f;
        for (int k = lane; k < 1056; k += 64) m = fmaxf(m, logits_s[qi * LSTR + k]);
#pragma unroll
        for (int o = 32; o > 0; o >>= 1) m = fmaxf(m, __shfl_xor(m, o));
        float sum = 0.f;
        for (int k = lane; k < 1056; k += 64) {
            const float p = __expf(logits_s[qi * LSTR + k] - m);
            logits_s[qi * LSTR + k] = p;
            sum += p;
        }
#pragma unroll
        for (int o = 32; o > 0; o >>= 1) sum += __shfl_xor(sum, o);
        if (lane == 0) srow_s[qi] = sum;
    }
    __syncthreads();

    // ---- pass 3: PV, split (d-frag f) x (k-half h) ----
    const int f = w & 3, h = w >> 2;
    const int cstart = h ? 17 : 0, cend = h ? 33 : 17;
    const unsigned short* vrow = vtbf + ((size_t)bh * 64 + f * 16 + frow) * 1056 + fcol;
    f32x4 acc = (f32x4){0.f, 0.f, 0.f, 0.f};
    for (int c = cstart; c < cend; ++c) {
        const float* pp = &logits_s[frow * LSTR + c * 32 + fcol];
        f32x4 p0 = *(const f32x4*)pp;
        f32x4 p1 = *(const f32x4*)(pp + 4);
        s16x8 pa;
        pa[0] = (short)f2bf(p0[0]); pa[1] = (short)f2bf(p0[1]);
        pa[2] = (short)f2bf(p0[2]); pa[3] = (short)f2bf(p0[3]);
        pa[4] = (short)f2bf(p1[0]); pa[5] = (short)f2bf(p1[1]);
        pa[6] = (short)f2bf(p1[2]); pa[7] = (short)f2bf(p1[3]);
        s16x8 vb = *(const s16x8*)(vrow + c * 32);
        acc = __builtin_amdgcn_mfma_f32_16x16x32_bf16(pa, vb, acc, 0, 0, 0);
    }
    const int qrow0 = (lane >> 4) * 4;
    if (h == 1) {
#pragma unroll
        for (int r = 0; r < 4; ++r) partial_s[f][qrow0 + r][frow] = acc[r];
    }
    __syncthreads();
    if (h == 0) {
#pragma unroll
        for (int r = 0; r < 4; ++r) {
            const int qrow = qrow0 + r, qg = q0 + qrow;
            if (qg < NPOOL) {
                const int d = f * 16 + frow;
                const float o = (acc[r] + partial_s[f][qrow][frow]) / srow_s[qrow]
                              + qpf[((size_t)bh * NPOOL + qg) * 64 + d];
                outp[((size_t)bi * NPOOL + qg) * DIMC + hh * 64 + d] = o;
            }
        }
    }
}

// ---------------------------------------------------------------------------
extern "C" void kernel_launch(void* const* d_in, const int* in_sizes, int n_in,
                              void* d_out, int out_size, void* d_ws, size_t ws_size,
                              hipStream_t stream) {
    const float* x     = (const float*)d_in[0];
    const float* wqkv  = (const float*)d_in[1];
    const float* dwq   = (const float*)d_in[2];
    const float* dwk   = (const float*)d_in[3];
    const float* dwv   = (const float*)d_in[4];
    const float* gq    = (const float*)d_in[5];
    const float* bq    = (const float*)d_in[6];
    const float* gk    = (const float*)d_in[7];
    const float* bk    = (const float*)d_in[8];
    const float* gv    = (const float*)d_in[9];
    const float* bv    = (const float*)d_in[10];
    const float* rph   = (const float*)d_in[11];
    const float* rpw   = (const float*)d_in[12];
    const float* wproj = (const float*)d_in[13];
    const float* bproj = (const float*)d_in[14];
    float* out = (float*)d_out;
    float* ws_f = (float*)d_ws;

    // Workspace layout (f32 units):
    //   [0, A)  qkv_bf u16 (16388x2304 = 18,878,976 f32-eq used); recycled
    //           after pool for relH/relW/outpre/outpre_bf/wproj_bf
    //   A = 37,757,952:
    //     qp    f32  A+0         (3,148,800)
    //     qp_bf u16  A+3,148,800 (1,597,440 f32-eq)  48 x 1040 x 64
    //     kp_bf u16  A+4,746,240 (1,622,016 f32-eq)  48 x 1056 x 64
    //     vt_bf u16  A+6,368,256 (1,622,016 f32-eq)  48 x 64 x 1056
    //     wqkv_bf u16 A+7,990,272 (884,736 f32-eq)
    //   x_bf u16 @ A (6,340,608 f32-eq) - dead after gemm1; pool overwrites.
    const size_t A = 37757952;
    unsigned short* qkv_bf = (unsigned short*)ws_f;
    float* qp = ws_f + A;
    unsigned short* qp_bf = (unsigned short*)(ws_f + A + 3148800);
    unsigned short* kp_bf = (unsigned short*)(ws_f + A + 4746240);
    unsigned short* vt_bf = (unsigned short*)(ws_f + A + 6368256);
    unsigned short* wqkv_bf = (unsigned short*)(ws_f + A + 7990272);
    unsigned short* x_bf = (unsigned short*)qp;
    float* relH   = ws_f;
    float* relW   = ws_f + 1572864;
    float* outpre = ws_f + 3145728;
    unsigned short* outpre_bf = (unsigned short*)(ws_f + 6294528);
    unsigned short* wproj_bf  = (unsigned short*)(ws_f + 7916544);

    // 0) zero V^T pad columns (whole buffer, 6.5 MB)
    hipMemsetAsync(vt_bf, 0, (size_t)48 * 64 * 1056 * 2, stream);
    // 1) convert + pad A, transpose + convert B for the qkv GEMM
    cvt_pad<<<(16512 * 96 + 255) / 256, 256, 0, stream>>>(x, x_bf, 16388, 16512 * 96);
    transpose_cvt<<<dim3(2304 / 32, 768 / 32), 256, 0, stream>>>(wqkv, wqkv_bf, 768, 2304);
    // 2) QKV GEMM (bf16 MFMA): (16388 x 768) @ (768 x 2304) -> bf16
    gemm_bf16<<<dim3(18, 129), 256, 0, stream>>>(x_bf, wqkv_bf, nullptr, qkv_bf, 16388, 2304, 768, 1);
    // 3) conv-pool + LayerNorm -> qp f32, qp/kp bf16, V^T bf16
    pool_ln_kernel<<<dim3(1025, 3, 4), 256, 0, stream>>>(qkv_bf, dwq, dwk, dwv,
                                                         gq, bq, gk, bk, gv, bv,
                                                         qp, qp_bf, kp_bf, vt_bf);
    // 4) rel_h / rel_w tables
    rel_kernel<<<dim3(12288), 256, 0, stream>>>(qp, rph, rpw, relH, relW);
    // 5) MFMA attention (8 waves) + residual -> outpre (b, tok, 768)
    attn_mfma<<<dim3(65, 48), 512, 0, stream>>>(qp_bf, kp_bf, vt_bf, qp, relH, relW, outpre);
    // 6) proj GEMM (bf16 MFMA): (4100 x 768) @ (768 x 768) + bias -> f32 out
    cvt_pad<<<(4224 * 96 + 255) / 256, 256, 0, stream>>>(outpre, outpre_bf, 4100, 4224 * 96);
    transpose_cvt<<<dim3(768 / 32, 768 / 32), 256, 0, stream>>>(wproj, wproj_bf, 768, 768);
    gemm_bf16<<<dim3(6, 33), 256, 0, stream>>>(outpre_bf, wproj_bf, bproj, out, 4100, 768, 768, 0);
}